// Round 8
// baseline (292.485 us; speedup 1.0000x reference)
//
#include <hip/hip_runtime.h>

// upfirdn2d specialized: up=2, down=1, pad0=2, eff trailing pad 2,
// 4x4 kernel, input (1024, 128, 128) f32 -> output (1024, 256, 256) f32.
//
// Polyphase: output (2r+py, 2c+px) mixes input rows {r-1,r} (py=0) or
// {r,r+1} (py=1), same in x. w[ky][kx] = kernel[3-ky][3-kx] (conv flip).
//
// R3 structure (1 input row per thread) widened to 8 cols/thread.
// NAMED SCALARS ONLY (R4 lesson: arrays -> scratch). Per thread:
// 3 rows x (2 float4 + 2 halo scalars) loads, 2x16 outputs, 8 f4 stores.

typedef float f4 __attribute__((ext_vector_type(4)));

// Load cols x0-1 .. x0+8 of row rr into A##0..A##9 (zero-padded at edges).
#define LDROW8(rr, A)                                                     \
  if ((rr) >= 0 && (rr) < H) {                                            \
    const float* row = xi + (rr) * W + x0;                                \
    const f4 v = *reinterpret_cast<const f4*>(row);                       \
    const f4 u = *reinterpret_cast<const f4*>(row + 4);                   \
    A##0 = (cg > 0) ? row[-1] : 0.f;                                      \
    A##1 = v.x; A##2 = v.y; A##3 = v.z; A##4 = v.w;                       \
    A##5 = u.x; A##6 = u.y; A##7 = u.z; A##8 = u.w;                       \
    A##9 = (cg < 15) ? row[8] : 0.f;                                      \
  } else {                                                                \
    A##0 = A##1 = A##2 = A##3 = A##4 = 0.f;                               \
    A##5 = A##6 = A##7 = A##8 = A##9 = 0.f;                               \
  }

// One output row (16 cols) from input rows A,B.
// even cols: ea*A[j] + eb*A[j+1] + ec*B[j] + ed*B[j+1]
// odd  cols: oa*A[j+1] + ob*A[j+2] + oc*B[j+1] + od*B[j+2]
#define EMITROW(A, B, ea, eb, ec, ed, oa, ob, oc, od, dst)                \
  {                                                                       \
    f4 e0, e1, e2, e3;                                                    \
    e0.x = ea*A##0 + eb*A##1 + ec*B##0 + ed*B##1;                         \
    e0.y = oa*A##1 + ob*A##2 + oc*B##1 + od*B##2;                         \
    e0.z = ea*A##1 + eb*A##2 + ec*B##1 + ed*B##2;                         \
    e0.w = oa*A##2 + ob*A##3 + oc*B##2 + od*B##3;                         \
    e1.x = ea*A##2 + eb*A##3 + ec*B##2 + ed*B##3;                         \
    e1.y = oa*A##3 + ob*A##4 + oc*B##3 + od*B##4;                         \
    e1.z = ea*A##3 + eb*A##4 + ec*B##3 + ed*B##4;                         \
    e1.w = oa*A##4 + ob*A##5 + oc*B##4 + od*B##5;                         \
    e2.x = ea*A##4 + eb*A##5 + ec*B##4 + ed*B##5;                         \
    e2.y = oa*A##5 + ob*A##6 + oc*B##5 + od*B##6;                         \
    e2.z = ea*A##5 + eb*A##6 + ec*B##5 + ed*B##6;                         \
    e2.w = oa*A##6 + ob*A##7 + oc*B##6 + od*B##7;                         \
    e3.x = ea*A##6 + eb*A##7 + ec*B##6 + ed*B##7;                         \
    e3.y = oa*A##7 + ob*A##8 + oc*B##7 + od*B##8;                         \
    e3.z = ea*A##7 + eb*A##8 + ec*B##7 + ed*B##8;                         \
    e3.w = oa*A##8 + ob*A##9 + oc*B##8 + od*B##9;                         \
    __builtin_nontemporal_store(e0, reinterpret_cast<f4*>(dst));          \
    __builtin_nontemporal_store(e1, reinterpret_cast<f4*>((dst) + 4));    \
    __builtin_nontemporal_store(e2, reinterpret_cast<f4*>((dst) + 8));    \
    __builtin_nontemporal_store(e3, reinterpret_cast<f4*>((dst) + 12));   \
  }

__global__ __launch_bounds__(256) void upfirdn2d_up2_kernel(
    const float* __restrict__ x, const float* __restrict__ kern,
    float* __restrict__ out) {
  constexpr int H = 128, W = 128, OW = 256;

  const int tid = threadIdx.x;
  const int cg  = tid & 15;                             // 8-col group 0..15
  const int r   = ((blockIdx.x & 7) << 4) | (tid >> 4); // input row 0..127
  const int img = blockIdx.x >> 3;                      // 0..1023

  // Flipped 4x4 kernel weights (uniform -> scalar regs).
  const float w00 = kern[15], w01 = kern[14], w02 = kern[13], w03 = kern[12];
  const float w10 = kern[11], w11 = kern[10], w12 = kern[9],  w13 = kern[8];
  const float w20 = kern[7],  w21 = kern[6],  w22 = kern[5],  w23 = kern[4];
  const float w30 = kern[3],  w31 = kern[2],  w32 = kern[1],  w33 = kern[0];

  const float* xi = x + (size_t)img * H * W;
  const int x0 = cg << 3;  // first input col of this thread

  float t0, t1, t2, t3, t4, t5, t6, t7, t8, t9;
  float m0, m1, m2, m3, m4, m5, m6, m7, m8, m9;
  float b0, b1, b2, b3, b4, b5, b6, b7, b8, b9;

  LDROW8(r - 1, t);
  LDROW8(r,     m);
  LDROW8(r + 1, b);

  float* orow0 = out + (size_t)img * OW * OW + (size_t)(2 * r) * OW + 2 * x0;
  float* orow1 = orow0 + OW;
  EMITROW(t, m, w00, w02, w20, w22, w01, w03, w21, w23, orow0);
  EMITROW(m, b, w10, w12, w30, w32, w11, w13, w31, w33, orow1);
}

extern "C" void kernel_launch(void* const* d_in, const int* in_sizes, int n_in,
                              void* d_out, int out_size, void* d_ws, size_t ws_size,
                              hipStream_t stream) {
  const float* x    = (const float*)d_in[0];
  const float* kern = (const float*)d_in[1];
  float* out        = (float*)d_out;
  // 1024 images x 8 blocks (16 input rows x 16 eight-col groups per block).
  upfirdn2d_up2_kernel<<<dim3(1024 * 8), dim3(256), 0, stream>>>(x, kern, out);
}

// Round 9
// 60.351 us; speedup vs baseline: 4.8464x; 4.8464x over previous
//
#include <hip/hip_runtime.h>

// upfirdn2d specialized: up=2, down=1, pad0=2, eff trailing pad 2,
// 4x4 kernel, input (1024, 128, 128) f32 -> output (1024, 256, 256) f32.
//
// R4/R8 lesson: strided partial-line NT stores -> ~2-3x HBM write
// amplification (WRITE_SIZE 495-737 MB vs 268 ideal). This version makes
// stores PERFECTLY dense: one wave = one full output row; each thread
// stores one f4 (lane-contiguous, 1 KB per store instruction).
//
// Polyphase per output row q (py=q&1, r=q>>1): rows rA=r-1+py (weight row
// py), rB=r+py (weight row 2+py). Output cols 4t..4t+3 need input cols
// 2t-1..2t+2 = one 4B-aligned f4 load per input row, edge-remapped.

typedef float f4 __attribute__((ext_vector_type(4)));
typedef f4 __attribute__((aligned(4))) f4u;  // 4B-aligned vector load

__global__ __launch_bounds__(256) void upfirdn2d_up2_kernel(
    const float* __restrict__ x, const float* __restrict__ kern,
    float* __restrict__ out) {
  constexpr int H = 128, W = 128, OW = 256;

  const int tid = threadIdx.x;
  const int t   = tid & 63;                               // col-group: out cols 4t..4t+3
  const int q   = ((blockIdx.x & 63) << 2) | (tid >> 6);  // output row 0..255 (wave-uniform)
  const int img = blockIdx.x >> 6;                        // 0..1023

  const int py = q & 1, r = q >> 1;
  const int rA = r - 1 + py;   // -1..127
  const int rB = r + py;       //  0..128

  // Flipped 4x4 kernel: w[ky][kx] = kern[(3-ky)*4 + (3-kx)].
  const float w00 = kern[15], w01 = kern[14], w02 = kern[13], w03 = kern[12];
  const float w10 = kern[11], w11 = kern[10], w12 = kern[9],  w13 = kern[8];
  const float w20 = kern[7],  w21 = kern[6],  w22 = kern[5],  w23 = kern[4];
  const float w30 = kern[3],  w31 = kern[2],  w32 = kern[1],  w33 = kern[0];
  // A-row weights = flipped row py; B-row = flipped row 2+py (wave-uniform).
  const float wA0 = py ? w10 : w00, wA1 = py ? w11 : w01;
  const float wA2 = py ? w12 : w02, wA3 = py ? w13 : w03;
  const float wB0 = py ? w30 : w20, wB1 = py ? w31 : w21;
  const float wB2 = py ? w32 : w22, wB3 = py ? w33 : w23;

  const float* xi = x + (size_t)img * H * W;
  int c0 = 2 * t - 1;                       // want cols c0..c0+3
  c0 = c0 < 0 ? 0 : (c0 > W - 4 ? W - 4 : c0);  // clamp into the row

  f4 va = {0.f, 0.f, 0.f, 0.f}, vb = {0.f, 0.f, 0.f, 0.f};
  if (rA >= 0) va = *reinterpret_cast<const f4u*>(xi + rA * W + c0);
  if (rB < H)  vb = *reinterpret_cast<const f4u*>(xi + rB * W + c0);

  // Remap to a[0..3] = in[2t-1 .. 2t+2] with zero padding at image edges.
  const bool L = (t == 0), R = (t == 63);
  const float a0 = L ? 0.f  : (R ? va.y : va.x);
  const float a1 = L ? va.x : (R ? va.z : va.y);
  const float a2 = L ? va.y : (R ? va.w : va.z);
  const float a3 = L ? va.z : (R ? 0.f  : va.w);
  const float b0 = L ? 0.f  : (R ? vb.y : vb.x);
  const float b1 = L ? vb.x : (R ? vb.z : vb.y);
  const float b2 = L ? vb.y : (R ? vb.w : vb.z);
  const float b3 = L ? vb.z : (R ? 0.f  : vb.w);

  f4 o;
  o.x = wA0 * a0 + wA2 * a1 + wB0 * b0 + wB2 * b1;  // col 4t   (even)
  o.y = wA1 * a1 + wA3 * a2 + wB1 * b1 + wB3 * b2;  // col 4t+1 (odd)
  o.z = wA0 * a1 + wA2 * a2 + wB0 * b1 + wB2 * b2;  // col 4t+2 (even)
  o.w = wA1 * a2 + wA3 * a3 + wB1 * b2 + wB3 * b3;  // col 4t+3 (odd)

  float* dst = out + (size_t)img * OW * OW + (size_t)q * OW + 4 * t;
  __builtin_nontemporal_store(o, reinterpret_cast<f4*>(dst));
}

extern "C" void kernel_launch(void* const* d_in, const int* in_sizes, int n_in,
                              void* d_out, int out_size, void* d_ws, size_t ws_size,
                              hipStream_t stream) {
  const float* x    = (const float*)d_in[0];
  const float* kern = (const float*)d_in[1];
  float* out        = (float*)d_out;
  // 1024 images x 64 blocks; block = 4 output rows x 64 col-groups.
  // One wave = one full 1 KB output row -> dense stores.
  upfirdn2d_up2_kernel<<<dim3(1024 * 64), dim3(256), 0, stream>>>(x, kern, out);
}

// Round 10
// 57.124 us; speedup vs baseline: 5.1202x; 1.0565x over previous
//
#include <hip/hip_runtime.h>

// upfirdn2d specialized: up=2, down=1, pad0=2, eff trailing pad 2,
// 4x4 kernel, input (1024, 128, 128) f32 -> output (1024, 256, 256) f32.
//
// R9 (60.4us) lesson: store density is everything -- one wave must cover
// contiguous 1KB output rows. This version: each thread computes cols
// 4t..4t+3 of BOTH output rows 2r and 2r+1 (they share input row r):
// 3 row-loads instead of 4, remap amortized over 2 stores, no runtime
// phase-select on weights. Both stores remain wave-dense (64 x 16B = 1KB).
//
// Polyphase: out row 2r   = w0x * in[r-1] + w2x * in[r]   (flipped rows)
//            out row 2r+1 = w1x * in[r]   + w3x * in[r+1]
// Out cols 4t..4t+3 need input cols 2t-1..2t+2: one 4B-aligned f4 load
// per row, clamped at edges and remapped with cndmasks.

typedef float f4 __attribute__((ext_vector_type(4)));
typedef f4 __attribute__((aligned(4))) f4u;  // 4B-aligned vector load

__global__ __launch_bounds__(256) void upfirdn2d_up2_kernel(
    const float* __restrict__ x, const float* __restrict__ kern,
    float* __restrict__ out) {
  constexpr int H = 128, W = 128, OW = 256;

  const int tid = threadIdx.x;
  const int t   = tid & 63;                               // out cols 4t..4t+3
  const int r   = ((blockIdx.x & 31) << 2) | (tid >> 6);  // input row 0..127 (wave-uniform)
  const int img = blockIdx.x >> 5;                        // 0..1023

  // Flipped 4x4 kernel: w[ky][kx] = kern[(3-ky)*4 + (3-kx)].
  const float w00 = kern[15], w01 = kern[14], w02 = kern[13], w03 = kern[12];
  const float w10 = kern[11], w11 = kern[10], w12 = kern[9],  w13 = kern[8];
  const float w20 = kern[7],  w21 = kern[6],  w22 = kern[5],  w23 = kern[4];
  const float w30 = kern[3],  w31 = kern[2],  w32 = kern[1],  w33 = kern[0];

  const float* xi = x + (size_t)img * H * W;
  int c0 = 2 * t - 1;                            // want cols c0..c0+3
  c0 = c0 < 0 ? 0 : (c0 > W - 4 ? W - 4 : c0);   // clamp into the row

  f4 va = {0.f, 0.f, 0.f, 0.f}, vb = {0.f, 0.f, 0.f, 0.f};
  const f4 vm = *reinterpret_cast<const f4u*>(xi + r * W + c0);
  if (r > 0)     va = *reinterpret_cast<const f4u*>(xi + (r - 1) * W + c0);
  if (r < H - 1) vb = *reinterpret_cast<const f4u*>(xi + (r + 1) * W + c0);

  // Remap to [0..3] = in[2t-1 .. 2t+2] with zero padding at image edges.
  const bool L = (t == 0), R = (t == 63);
  const float a0 = L ? 0.f  : (R ? va.y : va.x);
  const float a1 = L ? va.x : (R ? va.z : va.y);
  const float a2 = L ? va.y : (R ? va.w : va.z);
  const float a3 = L ? va.z : (R ? 0.f  : va.w);
  const float m0 = L ? 0.f  : (R ? vm.y : vm.x);
  const float m1 = L ? vm.x : (R ? vm.z : vm.y);
  const float m2 = L ? vm.y : (R ? vm.w : vm.z);
  const float m3 = L ? vm.z : (R ? 0.f  : vm.w);
  const float b0 = L ? 0.f  : (R ? vb.y : vb.x);
  const float b1 = L ? vb.x : (R ? vb.z : vb.y);
  const float b2 = L ? vb.y : (R ? vb.w : vb.z);
  const float b3 = L ? vb.z : (R ? 0.f  : vb.w);

  f4 o, p;  // output rows 2r and 2r+1, cols 4t..4t+3
  o.x = w00 * a0 + w02 * a1 + w20 * m0 + w22 * m1;
  o.y = w01 * a1 + w03 * a2 + w21 * m1 + w23 * m2;
  o.z = w00 * a1 + w02 * a2 + w20 * m1 + w22 * m2;
  o.w = w01 * a2 + w03 * a3 + w21 * m2 + w23 * m3;
  p.x = w10 * m0 + w12 * m1 + w30 * b0 + w32 * b1;
  p.y = w11 * m1 + w13 * m2 + w31 * b1 + w33 * b2;
  p.z = w10 * m1 + w12 * m2 + w30 * b1 + w32 * b2;
  p.w = w11 * m2 + w13 * m3 + w31 * b2 + w33 * b3;

  float* dst = out + (size_t)img * OW * OW + (size_t)(2 * r) * OW + 4 * t;
  __builtin_nontemporal_store(o, reinterpret_cast<f4*>(dst));
  __builtin_nontemporal_store(p, reinterpret_cast<f4*>(dst + OW));
}

extern "C" void kernel_launch(void* const* d_in, const int* in_sizes, int n_in,
                              void* d_out, int out_size, void* d_ws, size_t ws_size,
                              hipStream_t stream) {
  const float* x    = (const float*)d_in[0];
  const float* kern = (const float*)d_in[1];
  float* out        = (float*)d_out;
  // 1024 images x 32 blocks; block = 4 waves, each wave = one input row
  // -> two full dense 1KB output rows.
  upfirdn2d_up2_kernel<<<dim3(1024 * 32), dim3(256), 0, stream>>>(x, kern, out);
}

// Round 11
// 55.248 us; speedup vs baseline: 5.2941x; 1.0340x over previous
//
#include <hip/hip_runtime.h>

// upfirdn2d specialized: up=2, down=1, pad0=2, eff trailing pad 2,
// 4x4 kernel, input (1024, 128, 128) f32 -> output (1024, 256, 256) f32.
//
// Lessons: (R8/R9) every store instruction must be wave-dense -- 64 lanes
// x 16B = one contiguous 1KB output row. (R10) sharing input rows across
// output rows amortizes loads+remap. This version: one thread = input
// row-pair (r0, r0+1) -> 4 output rows. 4 loads + 4 dense stores per
// 64B output (vs R10's 3+2 per 32B). Named scalars only.
//
// Polyphase (flipped kernel rows): out 2r   = w0x*in[r-1] + w2x*in[r]
//                                  out 2r+1 = w1x*in[r]   + w3x*in[r+1]
// Out cols 4t..4t+3 need in cols 2t-1..2t+2: one 4B-aligned f4 load per
// row, clamped at row ends, remapped with cndmasks.

typedef float f4 __attribute__((ext_vector_type(4)));
typedef f4 __attribute__((aligned(4))) f4u;  // 4B-aligned vector load

// Remap clamped load v to A0..A3 = in[2t-1 .. 2t+2] (zero-pad at edges).
#define REMAP(v, A)                                                       \
  const float A##0 = L ? 0.f : (R ? v.y : v.x);                           \
  const float A##1 = L ? v.x : (R ? v.z : v.y);                           \
  const float A##2 = L ? v.y : (R ? v.w : v.z);                           \
  const float A##3 = L ? v.z : (R ? 0.f : v.w);

// One output row (cols 4t..4t+3) from remapped rows A (upper) and B
// (lower): even cols use (u0,u2,l0,l2), odd cols (u1,u3,l1,l3).
#define OUTROW(A, B, u0, u1, u2, u3, l0, l1, l2, l3, dst)                 \
  {                                                                       \
    f4 o;                                                                 \
    o.x = u0*A##0 + u2*A##1 + l0*B##0 + l2*B##1;                          \
    o.y = u1*A##1 + u3*A##2 + l1*B##1 + l3*B##2;                          \
    o.z = u0*A##1 + u2*A##2 + l0*B##1 + l2*B##2;                          \
    o.w = u1*A##2 + u3*A##3 + l1*B##2 + l3*B##3;                          \
    __builtin_nontemporal_store(o, reinterpret_cast<f4*>(dst));           \
  }

__global__ __launch_bounds__(256) void upfirdn2d_up2_kernel(
    const float* __restrict__ x, const float* __restrict__ kern,
    float* __restrict__ out) {
  constexpr int H = 128, W = 128, OW = 256;

  const int tid = threadIdx.x;
  const int t   = tid & 63;                               // out cols 4t..4t+3
  const int rp  = ((blockIdx.x & 15) << 2) | (tid >> 6);  // row-pair 0..63 (wave-uniform)
  const int img = blockIdx.x >> 4;                        // 0..1023
  const int r0  = rp << 1;                                // 0,2,..,126

  // Flipped 4x4 kernel: w[ky][kx] = kern[(3-ky)*4 + (3-kx)].
  const float w00 = kern[15], w01 = kern[14], w02 = kern[13], w03 = kern[12];
  const float w10 = kern[11], w11 = kern[10], w12 = kern[9],  w13 = kern[8];
  const float w20 = kern[7],  w21 = kern[6],  w22 = kern[5],  w23 = kern[4];
  const float w30 = kern[3],  w31 = kern[2],  w32 = kern[1],  w33 = kern[0];

  const float* xi = x + (size_t)img * H * W;
  int c0 = 2 * t - 1;                            // want cols c0..c0+3
  c0 = c0 < 0 ? 0 : (c0 > W - 4 ? W - 4 : c0);   // clamp into the row

  // Rows r0-1, r0, r0+1, r0+2 (r0 and r0+1 always in-bounds).
  f4 va = {0.f, 0.f, 0.f, 0.f}, vc = {0.f, 0.f, 0.f, 0.f};
  const f4 vm = *reinterpret_cast<const f4u*>(xi + r0 * W + c0);
  const f4 vb = *reinterpret_cast<const f4u*>(xi + (r0 + 1) * W + c0);
  if (r0 > 0)     va = *reinterpret_cast<const f4u*>(xi + (r0 - 1) * W + c0);
  if (r0 + 2 < H) vc = *reinterpret_cast<const f4u*>(xi + (r0 + 2) * W + c0);

  const bool L = (t == 0), R = (t == 63);
  REMAP(va, a);
  REMAP(vm, m);
  REMAP(vb, b);
  REMAP(vc, d);

  float* dst = out + (size_t)img * OW * OW + (size_t)(2 * r0) * OW + 4 * t;
  OUTROW(a, m, w00, w01, w02, w03, w20, w21, w22, w23, dst);          // row 2r0
  OUTROW(m, b, w10, w11, w12, w13, w30, w31, w32, w33, dst + OW);     // row 2r0+1
  OUTROW(m, b, w00, w01, w02, w03, w20, w21, w22, w23, dst + 2*OW);   // row 2r0+2
  OUTROW(b, d, w10, w11, w12, w13, w30, w31, w32, w33, dst + 3*OW);   // row 2r0+3
}

extern "C" void kernel_launch(void* const* d_in, const int* in_sizes, int n_in,
                              void* d_out, int out_size, void* d_ws, size_t ws_size,
                              hipStream_t stream) {
  const float* x    = (const float*)d_in[0];
  const float* kern = (const float*)d_in[1];
  float* out        = (float*)d_out;
  // 1024 images x 16 blocks; block = 4 waves, each wave = one input
  // row-pair -> four full dense 1KB output rows.
  upfirdn2d_up2_kernel<<<dim3(1024 * 16), dim3(256), 0, stream>>>(x, kern, out);
}